// Round 12
// baseline (345.110 us; speedup 1.0000x reference)
//
#include <hip/hip_runtime.h>
#include <cstdint>
#include <cstddef>

#define HEADS   8
#define NFEAT   256
#define NOUT    128
#define NEG     0.2f
#define EPSV    1e-5f

typedef unsigned short ushort_t;
typedef __attribute__((ext_vector_type(8))) short s8v;   // 8 bf16 = 4 VGPR
typedef __attribute__((ext_vector_type(4))) float f4v;   // MFMA accum

static __device__ __forceinline__ float lrelu(float x) { return x > 0.f ? x : NEG * x; }

static __device__ __forceinline__ float bf2f(ushort_t u) {
    union { unsigned int i; float f; } v; v.i = ((unsigned int)u) << 16; return v.f;
}
static __device__ __forceinline__ ushort_t f2bf(float f) {
    union { float f; unsigned int i; } v; v.f = f;
    unsigned int x = v.i;
    return (ushort_t)((x + 0x7fff + ((x >> 16) & 1)) >> 16);   // RNE
}
static __device__ __forceinline__ float bits2f(unsigned int u) {
    union { unsigned int i; float f; } v; v.i = u; return v.f;
}
static __device__ __forceinline__ unsigned int f2bits(float f) {
    union { float f; unsigned int i; } v; v.f = f; return v.i;
}

// truncation hi/lo split of 2 floats packed into hi-word / lo-word uints
static __device__ __forceinline__ void split2(float v0, float v1,
                                              unsigned int& hw, unsigned int& lw) {
    unsigned int x0 = f2bits(v0), x1 = f2bits(v1);
    unsigned int h1b = x1 & 0xffff0000u;
    float lo0 = v0 - bits2f(x0 & 0xffff0000u);
    float lo1 = v1 - bits2f(h1b);
    hw = (x0 >> 16) | h1b;
    lw = (f2bits(lo0) >> 16) | (f2bits(lo1) & 0xffff0000u);
}

// wave-local int64-vs-int32 detection (deterministic, identical in every wave)
static __device__ __forceinline__ int detect64(const int* __restrict__ ei, int E) {
    int lane = threadIdx.x & 63;
    long idx = 2L * ((long)lane * (E / 64)) + 1;
    int v = ei[idx];
    unsigned long long ball = __ballot(v == 0);
    return (ball == ~0ull) ? 1 : 0;
}

// ---------------------------------------------------------------------------
// fused: edge-count (CSR histogram) + W hi/lo fragment-pack + x hi/lo
// fragment-pack (three disjoint block ranges).
// Packed-A layout: elem((row,k)) = rt*16384 + kbi*2048 + mf*512 + lane*8 + e
//   rt=row/64, mf=(row%64)/16, lj=row%16, kbi=k/32, lk=(k%32)/8, e=k%8,
//   lane=lk*16+lj  — matches k_mm's per-lane fragment fetch exactly.
__global__ void k_prep(const int* __restrict__ ei, int* __restrict__ counts,
                       int E, int n, int cblocks, int pblocks,
                       const float* __restrict__ W1, const float* __restrict__ W2,
                       ushort_t* __restrict__ Wh1, ushort_t* __restrict__ Wl1,
                       ushort_t* __restrict__ Wh2, ushort_t* __restrict__ Wl2,
                       const float* __restrict__ x,
                       ushort_t* __restrict__ Xh, ushort_t* __restrict__ Xl) {
    if (blockIdx.x < (unsigned)cblocks) {
        int is64 = detect64(ei, E);
        int i = blockIdx.x * 256 + threadIdx.x;
        if (i < E) {
            int d = ei[(size_t)(E + i) << is64];
            atomicAdd(&counts[d], 1);
        } else if (i < E + n) {
            atomicAdd(&counts[i - E], 1);
        }
    } else if (blockIdx.x < (unsigned)(cblocks + pblocks)) {
        int gid = (blockIdx.x - cblocks) * 256 + threadIdx.x;
        const float* W; ushort_t* Wh; ushort_t* Wl; int M;
        if (gid < 256 * 256) { W = W1; Wh = Wh1; Wl = Wl1; M = 256; }
        else { gid -= 256 * 256; if (gid >= 256 * 128) return; W = W2; Wh = Wh2; Wl = Wl2; M = 128; }
        int k = gid / M, nn = gid - k * M;
        int ntile = nn >> 4, j = nn & 15, kc = k >> 3, e = k & 7;
        int p = ((ntile * 32 + kc) * 16 + j) * 8 + e;     // K=256 -> K/8=32
        float v = W[(size_t)k * M + nn];
        ushort_t hi = f2bf(v);
        float r = v - bf2f(hi);
        Wh[p] = hi;
        Wl[p] = f2bf(r);
    } else {
        int gid = (blockIdx.x - cblocks - pblocks) * 256 + threadIdx.x;
        if (gid >= n * 32) return;
        int row = gid >> 5, k8 = gid & 31;
        const float* xp = &x[(size_t)row * 256 + k8 * 8];
        float4 v0 = *reinterpret_cast<const float4*>(xp);
        float4 v1 = *reinterpret_cast<const float4*>(xp + 4);
        unsigned int hw[4], lw[4];
        split2(v0.x, v0.y, hw[0], lw[0]);
        split2(v0.z, v0.w, hw[1], lw[1]);
        split2(v1.x, v1.y, hw[2], lw[2]);
        split2(v1.z, v1.w, hw[3], lw[3]);
        int rt = row >> 6, mf = (row & 63) >> 4, lj = row & 15;
        size_t po = (size_t)rt * 16384 + (k8 >> 2) * 2048 + mf * 512
                  + ((k8 & 3) * 16 + lj) * 8;
        uint4 hv = {hw[0], hw[1], hw[2], hw[3]};
        uint4 lv = {lw[0], lw[1], lw[2], lw[3]};
        *reinterpret_cast<uint4*>(&Xh[po]) = hv;
        *reinterpret_cast<uint4*>(&Xl[po]) = lv;
    }
}

__global__ __launch_bounds__(1024) void k_scan1(const int* __restrict__ counts,
                                                int* __restrict__ incl,
                                                int* __restrict__ bsum, int n) {
    int t = threadIdx.x, i = blockIdx.x * 1024 + t;
    int lane = t & 63, w = t >> 6;
    int v = (i < n) ? counts[i] : 0;
    int sv = v;
#pragma unroll
    for (int o = 1; o < 64; o <<= 1) { int u = __shfl_up(sv, o, 64); if (lane >= o) sv += u; }
    __shared__ int wsum[16];
    if (lane == 63) wsum[w] = sv;
    __syncthreads();
    if (w == 0) {
        int bs = (lane < 16) ? wsum[lane] : 0;
#pragma unroll
        for (int o = 1; o < 16; o <<= 1) { int u = __shfl_up(bs, o, 64); if (lane >= o) bs += u; }
        if (lane < 16) wsum[lane] = bs;
    }
    __syncthreads();
    int pre = (w > 0) ? wsum[w - 1] : 0;
    sv += pre;
    if (i < n) incl[i] = sv;
    if (t == 1023) bsum[blockIdx.x] = sv;   // raw block total
}

// scan3 with folded block-sum prefix
__global__ void k_scan3(const int* __restrict__ incl, const int* __restrict__ bsum,
                        const int* __restrict__ counts,
                        int* __restrict__ offs, int* __restrict__ cursor, int n) {
    __shared__ int pre_s;
    int chunk = blockIdx.x >> 2;            // 256-thr blocks, scan1 blocks = 1024
    if (threadIdx.x == 0) {
        int s = 0;
        for (int j = 0; j < chunk; ++j) s += bsum[j];
        pre_s = s;
    }
    __syncthreads();
    int i = blockIdx.x * 256 + threadIdx.x;
    if (i < n) {
        int v = incl[i] + pre_s;
        offs[i + 1] = v;
        cursor[i] = v - counts[i];
    }
    if (i == 0) offs[0] = 0;
}

__global__ void k_fill(const int* __restrict__ ei, int* __restrict__ cursor,
                       int* __restrict__ esrc, int E, int n) {
    int is64 = detect64(ei, E);
    int i = blockIdx.x * blockDim.x + threadIdx.x;
    if (i >= E + n) return;
    int s, d;
    if (i < E) { s = ei[(size_t)i << is64]; d = ei[(size_t)(E + i) << is64]; }
    else       { s = i - E; d = s; }
    int p = atomicAdd(&cursor[d], 1);
    esrc[p] = s;
}

// ---------------------------------------------------------------------------
// MFMA GEMM v5: LDS-free, barrier-free. A pre-packed (hi/lo) in fragment
// order; W pre-packed. Per K-step: 8 A-loads + 4 B-loads + 24 MFMAs.
// Fused attention-logit epilogue as before.
template <int MOUT>
__global__ __launch_bounds__(256) void k_mm(const ushort_t* __restrict__ Aph,
                                            const ushort_t* __restrict__ Apl,
                                            const ushort_t* __restrict__ Wh,
                                            const ushort_t* __restrict__ Wl,
                                            ushort_t* __restrict__ C,
                                            const float* __restrict__ att_s,
                                            const float* __restrict__ att_d,
                                            float* __restrict__ as_o,
                                            float* __restrict__ ad_o, int n) {
    const int t = threadIdx.x;
    const int lane = t & 63, w = t >> 6;     // w = column strip 0..3
    const int r0 = blockIdx.x * 64;
    const int lj = lane & 15, lk = lane >> 4;

    f4v acc[4][2];
#pragma unroll
    for (int a = 0; a < 4; ++a)
#pragma unroll
        for (int b = 0; b < 2; ++b) { f4v z = {0.f, 0.f, 0.f, 0.f}; acc[a][b] = z; }

    const size_t abase = (size_t)blockIdx.x * 16384 + (size_t)lane * 8;

#pragma unroll
    for (int kbi = 0; kbi < 8; ++kbi) {
        s8v ah[4], al[4];
#pragma unroll
        for (int mf = 0; mf < 4; ++mf) {
            size_t ao = abase + kbi * 2048 + mf * 512;
            ah[mf] = *reinterpret_cast<const s8v*>(&Aph[ao]);
            al[mf] = *reinterpret_cast<const s8v*>(&Apl[ao]);
        }
        s8v bh[2], bl[2];
#pragma unroll
        for (int nf = 0; nf < 2; ++nf) {
            int ntile = (MOUT == 256 ? blockIdx.y * 8 : 0) + w * 2 + nf;
            size_t boff = ((size_t)(ntile * 32 + kbi * 4 + lk) * 16 + lj) * 8;
            bh[nf] = *reinterpret_cast<const s8v*>(&Wh[boff]);
            bl[nf] = *reinterpret_cast<const s8v*>(&Wl[boff]);
        }
#pragma unroll
        for (int nf = 0; nf < 2; ++nf)
#pragma unroll
            for (int mf = 0; mf < 4; ++mf) {
                acc[mf][nf] = __builtin_amdgcn_mfma_f32_16x16x32_bf16(ah[mf], bh[nf], acc[mf][nf], 0, 0, 0);
                acc[mf][nf] = __builtin_amdgcn_mfma_f32_16x16x32_bf16(ah[mf], bl[nf], acc[mf][nf], 0, 0, 0);
                acc[mf][nf] = __builtin_amdgcn_mfma_f32_16x16x32_bf16(al[mf], bh[nf], acc[mf][nf], 0, 0, 0);
            }
    }

    const int colw = (MOUT == 256 ? blockIdx.y * 128 : 0) + w * 32;

    // C write (bf16, row-major for the gather kernels)
#pragma unroll
    for (int mf = 0; mf < 4; ++mf) {
        int rr = r0 + mf * 16 + lk * 4;
#pragma unroll
        for (int nf = 0; nf < 2; ++nf) {
            int cc = colw + nf * 16 + lj;
#pragma unroll
            for (int r = 0; r < 4; ++r) {
                if (rr + r < n) C[(size_t)(rr + r) * MOUT + cc] = f2bf(acc[mf][nf][r]);
            }
        }
    }

    // fused attention-logit epilogue (reduce over this wave's 32 cols)
    float asv[2], adv[2];
#pragma unroll
    for (int nf = 0; nf < 2; ++nf) {
        asv[nf] = att_s[colw + nf * 16 + lj];
        adv[nf] = att_d[colw + nf * 16 + lj];
    }
#pragma unroll
    for (int mf = 0; mf < 4; ++mf) {
        int rr = r0 + mf * 16 + lk * 4;
#pragma unroll
        for (int r = 0; r < 4; ++r) {
            float ss = acc[mf][0][r] * asv[0] + acc[mf][1][r] * asv[1];
            float sd = acc[mf][0][r] * adv[0] + acc[mf][1][r] * adv[1];
#pragma unroll
            for (int o = 1; o < 16; o <<= 1) {
                ss += __shfl_xor(ss, o, 64); sd += __shfl_xor(sd, o, 64);
            }
            if (lj == 0 && rr + r < n) {
                if (MOUT == 256) {
                    int head = (colw >> 5);
                    as_o[(size_t)(rr + r) * 8 + head] = ss;
                    ad_o[(size_t)(rr + r) * 8 + head] = sd;
                } else {
                    atomicAdd(&as_o[rr + r], ss);
                    atomicAdd(&ad_o[rr + r], sd);
                }
            }
        }
    }
}

// ---------------------------------------------------------------------------
// layer-1 aggregation (round-10 structure, VGPR-lean): half-wave per edge;
// exp once per (edge,head) in phase A. Output written PACKED (hi/lo bf16,
// fragment order) so layer-2 k_mm needs no staging.
__global__ __launch_bounds__(128) void k_agg1(const ushort_t* __restrict__ h1,
                                              const float* __restrict__ as1,
                                              const float* __restrict__ ad1,
                                              const int* __restrict__ offs,
                                              const int* __restrict__ esrc,
                                              const float* __restrict__ b1,
                                              ushort_t* __restrict__ Oh,
                                              ushort_t* __restrict__ Ol, int n, int tot) {
    int wid = (blockIdx.x * 128 + threadIdx.x) >> 6;
    int lane = threadIdx.x & 63;
    if (wid >= n) return;
    int e0 = offs[wid], e1 = offs[wid + 1];
    int deg = e1 - e0;
    const int rt = wid >> 6, mfr = (wid & 63) >> 4, ljr = wid & 15;

    if (deg <= 64) {
        const int l = lane & 31;          // channel-group lane
        const int h = lane >> 5;          // half: edge parity
        const int hd = l >> 2;            // head owning channels l*8..l*8+7
        const int cb = l * 8;

        int ei_idx = e0 + lane;
        int es = esrc[ei_idx < tot ? ei_idx : (tot - 1)];

        const int headA = lane >> 3, g = lane & 7;
        float adnA = ad1[(size_t)wid * 8 + headA];
        float a[8];
#pragma unroll
        for (int k = 0; k < 8; ++k) {
            int i = g + 8 * k;
            int s = __shfl(es, i, 64);
            a[k] = (i < deg) ? as1[(size_t)s * 8 + headA] : -1e30f;
        }
        float mx = a[0];
#pragma unroll
        for (int k = 1; k < 8; ++k) mx = fmaxf(mx, a[k]);
#pragma unroll
        for (int o = 1; o < 8; o <<= 1) mx = fmaxf(mx, __shfl_xor(mx, o, 64));
        float mA = lrelu(mx + adnA);
#pragma unroll
        for (int k = 0; k < 8; ++k)
            a[k] = __expf(lrelu(a[k] + adnA) - mA);   // p, 0 for padding

        float d = 0.f;
        float ac0 = 0.f, ac1 = 0.f, ac2 = 0.f, ac3 = 0.f;
        float ac4 = 0.f, ac5 = 0.f, ac6 = 0.f, ac7 = 0.f;
#pragma unroll
        for (int u = 0; u < 8; ++u) {
            if (8 * u < deg) {
#pragma unroll
                for (int v = 0; v < 4; ++v) {
                    int i = 8 * u + 2 * v + h;
                    int s = __shfl(es, i, 64);
                    float p = __shfl(a[u], hd * 8 + 2 * v + h, 64);
                    if (i < deg) {
                        uint4 hv = *reinterpret_cast<const uint4*>(&h1[(size_t)s * 256 + cb]);
                        d += p;
                        ac0 += p * bits2f(hv.x << 16);
                        ac1 += p * bits2f(hv.x & 0xffff0000u);
                        ac2 += p * bits2f(hv.y << 16);
                        ac3 += p * bits2f(hv.y & 0xffff0000u);
                        ac4 += p * bits2f(hv.z << 16);
                        ac5 += p * bits2f(hv.z & 0xffff0000u);
                        ac6 += p * bits2f(hv.w << 16);
                        ac7 += p * bits2f(hv.w & 0xffff0000u);
                    }
                }
            }
        }
        d   += __shfl_xor(d, 32, 64);
        ac0 += __shfl_xor(ac0, 32, 64); ac1 += __shfl_xor(ac1, 32, 64);
        ac2 += __shfl_xor(ac2, 32, 64); ac3 += __shfl_xor(ac3, 32, 64);
        ac4 += __shfl_xor(ac4, 32, 64); ac5 += __shfl_xor(ac5, 32, 64);
        ac6 += __shfl_xor(ac6, 32, 64); ac7 += __shfl_xor(ac7, 32, 64);
        if (lane < 32) {
            float inv = 1.f / (d + 1e-16f);
            float4 b0 = *reinterpret_cast<const float4*>(&b1[cb]);
            float4 b4 = *reinterpret_cast<const float4*>(&b1[cb + 4]);
            float o0 = fmaxf(ac0 * inv + b0.x, 0.f);
            float o1 = fmaxf(ac1 * inv + b0.y, 0.f);
            float o2 = fmaxf(ac2 * inv + b0.z, 0.f);
            float o3 = fmaxf(ac3 * inv + b0.w, 0.f);
            float o4 = fmaxf(ac4 * inv + b4.x, 0.f);
            float o5 = fmaxf(ac5 * inv + b4.y, 0.f);
            float o6 = fmaxf(ac6 * inv + b4.z, 0.f);
            float o7 = fmaxf(ac7 * inv + b4.w, 0.f);
            unsigned int hw[4], lw[4];
            split2(o0, o1, hw[0], lw[0]);
            split2(o2, o3, hw[1], lw[1]);
            split2(o4, o5, hw[2], lw[2]);
            split2(o6, o7, hw[3], lw[3]);
            size_t po = (size_t)rt * 16384 + (l >> 2) * 2048 + mfr * 512
                      + ((l & 3) * 16 + ljr) * 8;
            uint4 hv = {hw[0], hw[1], hw[2], hw[3]};
            uint4 lv = {lw[0], lw[1], lw[2], lw[3]};
            *reinterpret_cast<uint4*>(&Oh[po]) = hv;
            *reinterpret_cast<uint4*>(&Ol[po]) = lv;
        }
    } else {
        int head = lane >> 3;
        int g = lane & 7;
        int cb = lane * 4;
        float adn = ad1[(size_t)wid * 8 + head];
        float mx = -1e30f;
        for (int e = e0 + g; e < e1; e += 8)
            mx = fmaxf(mx, as1[(size_t)esrc[e] * 8 + head]);
#pragma unroll
        for (int o = 1; o < 8; o <<= 1) mx = fmaxf(mx, __shfl_xor(mx, o, 64));
        float m = lrelu(mx + adn);
        float d = 0.f, ax = 0.f, ay = 0.f, az = 0.f, aw = 0.f;
        for (int e = e0; e < e1; ++e) {
            int s = esrc[e];
            float p = __expf(lrelu(as1[(size_t)s * 8 + head] + adn) - m);
            ushort4 hv = *reinterpret_cast<const ushort4*>(&h1[(size_t)s * 256 + cb]);
            d += p;
            ax += p * bf2f(hv.x);
            ay += p * bf2f(hv.y);
            az += p * bf2f(hv.z);
            aw += p * bf2f(hv.w);
        }
        float inv = 1.f / (d + 1e-16f);
        float4 bb = *reinterpret_cast<const float4*>(&b1[cb]);
        float o0 = fmaxf(ax * inv + bb.x, 0.f);
        float o1 = fmaxf(ay * inv + bb.y, 0.f);
        float o2 = fmaxf(az * inv + bb.z, 0.f);
        float o3 = fmaxf(aw * inv + bb.w, 0.f);
        unsigned int hw0, lw0, hw1, lw1;
        split2(o0, o1, hw0, lw0);
        split2(o2, o3, hw1, lw1);
        int k8 = lane >> 1, e0c = (lane & 1) * 4;
        size_t po = (size_t)rt * 16384 + (k8 >> 2) * 2048 + mfr * 512
                  + ((k8 & 3) * 16 + ljr) * 8 + e0c;
        uint2 hv = {hw0, hw1}, lv = {lw0, lw1};
        *reinterpret_cast<uint2*>(&Oh[po]) = hv;
        *reinterpret_cast<uint2*>(&Ol[po]) = lv;
    }
}

// layer-2 aggregation (round-10 version): quarter-wave per edge; exp once.
__global__ __launch_bounds__(128) void k_agg2(const ushort_t* __restrict__ h2,
                                              const float* __restrict__ as2,
                                              const float* __restrict__ ad2,
                                              const int* __restrict__ offs,
                                              const int* __restrict__ esrc,
                                              const float* __restrict__ b2,
                                              float* __restrict__ out2, int n, int tot) {
    int wid = (blockIdx.x * 128 + threadIdx.x) >> 6;
    int lane = threadIdx.x & 63;
    if (wid >= n) return;
    float adn = ad2[wid];
    int e0 = offs[wid], e1 = offs[wid + 1];
    int deg = e1 - e0;

    if (deg <= 64) {
        const int l = lane & 15;
        const int q = lane >> 4;
        const int cb = l * 8;

        int ei_idx = e0 + lane;
        int es = esrc[ei_idx < tot ? ei_idx : (tot - 1)];
        float av0 = (lane < deg) ? as2[es] : -1e30f;
        float mx = av0;
#pragma unroll
        for (int o = 1; o < 64; o <<= 1) mx = fmaxf(mx, __shfl_xor(mx, o, 64));
        float m = lrelu(mx + adn);
        float p0 = __expf(lrelu(av0 + adn) - m);   // one exp per edge

        float d = 0.f;
        float ac0 = 0.f, ac1 = 0.f, ac2 = 0.f, ac3 = 0.f;
        float ac4 = 0.f, ac5 = 0.f, ac6 = 0.f, ac7 = 0.f;
#pragma unroll
        for (int u = 0; u < 4; ++u) {
            if (16 * u < deg) {
#pragma unroll
                for (int v = 0; v < 4; ++v) {
                    int i = 16 * u + 4 * v + q;
                    int s = __shfl(es, i, 64);
                    float p = __shfl(p0, i, 64);
                    if (i < deg) {
                        uint4 hv = *reinterpret_cast<const uint4*>(&h2[(size_t)s * 128 + cb]);
                        d += p;
                        ac0 += p * bits2f(hv.x << 16);
                        ac1 += p * bits2f(hv.x & 0xffff0000u);
                        ac2 += p * bits2f(hv.y << 16);
                        ac3 += p * bits2f(hv.y & 0xffff0000u);
                        ac4 += p * bits2f(hv.z << 16);
                        ac5 += p * bits2f(hv.z & 0xffff0000u);
                        ac6 += p * bits2f(hv.w << 16);
                        ac7 += p * bits2f(hv.w & 0xffff0000u);
                    }
                }
            }
        }
#pragma unroll
        for (int o = 16; o <= 32; o <<= 1) {
            d   += __shfl_xor(d, o, 64);
            ac0 += __shfl_xor(ac0, o, 64); ac1 += __shfl_xor(ac1, o, 64);
            ac2 += __shfl_xor(ac2, o, 64); ac3 += __shfl_xor(ac3, o, 64);
            ac4 += __shfl_xor(ac4, o, 64); ac5 += __shfl_xor(ac5, o, 64);
            ac6 += __shfl_xor(ac6, o, 64); ac7 += __shfl_xor(ac7, o, 64);
        }
        if (lane < 16) {
            float inv = 1.f / (d + 1e-16f);
            float4 b0 = *reinterpret_cast<const float4*>(&b2[cb]);
            float4 b4 = *reinterpret_cast<const float4*>(&b2[cb + 4]);
            float4 o0, o1;
            o0.x = fmaxf(ac0 * inv + b0.x, 0.f);
            o0.y = fmaxf(ac1 * inv + b0.y, 0.f);
            o0.z = fmaxf(ac2 * inv + b0.z, 0.f);
            o0.w = fmaxf(ac3 * inv + b0.w, 0.f);
            o1.x = fmaxf(ac4 * inv + b4.x, 0.f);
            o1.y = fmaxf(ac5 * inv + b4.y, 0.f);
            o1.z = fmaxf(ac6 * inv + b4.z, 0.f);
            o1.w = fmaxf(ac7 * inv + b4.w, 0.f);
            *reinterpret_cast<float4*>(&out2[(size_t)wid * 128 + cb]) = o0;
            *reinterpret_cast<float4*>(&out2[(size_t)wid * 128 + cb + 4]) = o1;
        }
    } else {
        int cb = lane * 2;
        float mx = -1e30f;
        for (int e = e0 + lane; e < e1; e += 64)
            mx = fmaxf(mx, as2[esrc[e]]);
#pragma unroll
        for (int o = 1; o < 64; o <<= 1) mx = fmaxf(mx, __shfl_xor(mx, o, 64));
        float m = lrelu(mx + adn);
        float d = 0.f, ax = 0.f, ay = 0.f;
        for (int e = e0; e < e1; ++e) {
            int s = esrc[e];
            float p = __expf(lrelu(as2[s] + adn) - m);
            ushort2 hv = *reinterpret_cast<const ushort2*>(&h2[(size_t)s * 128 + cb]);
            d += p;
            ax += p * bf2f(hv.x);
            ay += p * bf2f(hv.y);
        }
        float inv = 1.f / (d + 1e-16f);
        float o0 = fmaxf(ax * inv + b2[cb], 0.f);
        float o1 = fmaxf(ay * inv + b2[cb + 1], 0.f);
        float2 o = {o0, o1};
        *reinterpret_cast<float2*>(&out2[(size_t)wid * 128 + cb]) = o;
    }
}

// ---------------------------------------------------------------------------
__global__ __launch_bounds__(128) void k_bnstat(const float* __restrict__ out2,
                                                float* __restrict__ bnsum,
                                                float* __restrict__ bnsq, int n) {
    int c = threadIdx.x;
    float s = 0.f, q = 0.f;
    for (int r = blockIdx.x; r < n; r += gridDim.x) {
        float v = out2[(size_t)r * 128 + c];
        s += v;
        q += v * v;
    }
    atomicAdd(&bnsum[c], s);
    atomicAdd(&bnsq[c], q);
}

__global__ __launch_bounds__(256) void k_final(const float* __restrict__ out2,
                                               const float* __restrict__ bnsum,
                                               const float* __restrict__ bnsq,
                                               const float* __restrict__ bng,
                                               const float* __restrict__ bnb,
                                               const float* __restrict__ lng,
                                               const float* __restrict__ lnb,
                                               float* __restrict__ out, int n) {
    int wid = (blockIdx.x * blockDim.x + threadIdx.x) >> 6;
    int lane = threadIdx.x & 63;
    if (wid >= n) return;
    int c0 = lane, c1 = lane + 64;
    float invn = 1.f / (float)n;
    float mu0 = bnsum[c0] * invn, mu1 = bnsum[c1] * invn;
    float v0 = bnsq[c0] * invn - mu0 * mu0;
    float v1 = bnsq[c1] * invn - mu1 * mu1;
    float r0 = rsqrtf(v0 + EPSV), r1 = rsqrtf(v1 + EPSV);
    float x0 = out2[(size_t)wid * 128 + c0];
    float x1 = out2[(size_t)wid * 128 + c1];
    float y0 = (x0 - mu0) * r0 * bng[c0] + bnb[c0];
    float y1 = (x1 - mu1) * r1 * bng[c1] + bnb[c1];
    float s = y0 + y1, q = y0 * y0 + y1 * y1;
#pragma unroll
    for (int o = 1; o < 64; o <<= 1) { s += __shfl_xor(s, o, 64); q += __shfl_xor(q, o, 64); }
    float mu = s * (1.f / 128.f);
    float var = q * (1.f / 128.f) - mu * mu;
    float rr = rsqrtf(var + EPSV);
    out[(size_t)wid * 128 + c0] = (y0 - mu) * rr * lng[c0] + lnb[c0];
    out[(size_t)wid * 128 + c1] = (y1 - mu) * rr * lng[c1] + lnb[c1];
}

// ---------------------------------------------------------------------------
extern "C" void kernel_launch(void* const* d_in, const int* in_sizes, int n_in,
                              void* d_out, int out_size, void* d_ws, size_t ws_size,
                              hipStream_t stream) {
    const float* x    = (const float*)d_in[0];
    const int*   ei   = (const int*)d_in[1];
    const float* W1   = (const float*)d_in[2];
    const float* ats1 = (const float*)d_in[3];
    const float* atd1 = (const float*)d_in[4];
    const float* b1   = (const float*)d_in[5];
    const float* W2   = (const float*)d_in[6];
    const float* ats2 = (const float*)d_in[7];
    const float* atd2 = (const float*)d_in[8];
    const float* b2   = (const float*)d_in[9];
    const float* bng  = (const float*)d_in[10];
    const float* bnb  = (const float*)d_in[11];
    const float* lng  = (const float*)d_in[12];
    const float* lnb  = (const float*)d_in[13];

    const int n = in_sizes[0] / NFEAT;   // 50000
    const int E = in_sizes[1] / 2;       // 800000
    const int tot = E + n;
    const int gx = (n + 63) / 64;        // row tiles (782)

    auto align = [](size_t v) { return (v + 255) & ~(size_t)255; };
    char* ws = (char*)d_ws;
    size_t off = 0;
    ushort_t* h1 = (ushort_t*)(ws + off); off += align((size_t)n * 256 * 2);
    // packed A (x hi/lo); aliased as packed out1 (Oh/Ol) after k_mm<256>+agg1
    ushort_t* Xh = (ushort_t*)(ws + off); off += align((size_t)gx * 16384 * 2);
    ushort_t* Xl = (ushort_t*)(ws + off); off += align((size_t)gx * 16384 * 2);
    ushort_t* h2 = h1;
    float* out2 = (float*)(ws + off); off += align((size_t)n * 128 * 4);
    float* as1 = (float*)(ws + off); off += align((size_t)n * 8 * 4);
    float* ad1 = (float*)(ws + off); off += align((size_t)n * 8 * 4);
    // zero-region: counts[n] | bnsum[128] | bnsq[128] | as2[n] | ad2[n]
    int* counts = (int*)(ws + off); off += align((size_t)n * 12 + 1024);
    float* bnsum = (float*)(counts + n);
    float* bnsq  = bnsum + 128;
    float* as2   = bnsq + 128;
    float* ad2   = as2 + n;
    int* offs   = (int*)(ws + off); off += align((size_t)(n + 1) * 4);
    int* cursor = (int*)(ws + off); off += align((size_t)n * 4);
    int* esrc   = (int*)(ws + off); off += align((size_t)tot * 4);
    int* incl   = (int*)(ws + off); off += align((size_t)n * 4);
    int* bsum   = (int*)(ws + off); off += align(64 * 4);
    ushort_t* Wh1 = (ushort_t*)(ws + off); off += align((size_t)256 * 256 * 2);
    ushort_t* Wl1 = (ushort_t*)(ws + off); off += align((size_t)256 * 256 * 2);
    ushort_t* Wh2 = (ushort_t*)(ws + off); off += align((size_t)256 * 128 * 2);
    ushort_t* Wl2 = (ushort_t*)(ws + off); off += align((size_t)256 * 128 * 2);

    hipMemsetAsync(counts, 0, (size_t)n * 12 + 1024, stream);

    // fused count + W-pack + x-pack
    const int cblocks = (tot + 255) / 256;
    const int pblocks = (256 * 256 + 256 * 128 + 255) / 256;
    const int xblocks = (n * 32 + 255) / 256;
    k_prep<<<cblocks + pblocks + xblocks, 256, 0, stream>>>(
        ei, counts, E, n, cblocks, pblocks,
        W1, W2, Wh1, Wl1, Wh2, Wl2, x, Xh, Xl);
    int nsb = (n + 1023) / 1024;
    k_scan1<<<nsb, 1024, 0, stream>>>(counts, incl, bsum, n);
    k_scan3<<<(n + 255) / 256, 256, 0, stream>>>(incl, bsum, counts, offs, cursor, n);
    k_fill<<<(tot + 255) / 256, 256, 0, stream>>>(ei, cursor, esrc, E, n);

    // layer 1 (att logits fused into GEMM epilogue)
    k_mm<256><<<dim3(gx, 2), 256, 0, stream>>>(Xh, Xl, Wh1, Wl1, h1, ats1, atd1, as1, ad1, n);
    // agg1 writes packed out1 into Xh/Xl (dead after k_mm<256>)
    k_agg1<<<(n + 1) / 2, 128, 0, stream>>>(h1, as1, ad1, offs, esrc, b1, Xh, Xl, n, tot);

    // layer 2 (packed A = agg1 output; att logits fused, atomic partials)
    k_mm<128><<<dim3(gx, 1), 256, 0, stream>>>(Xh, Xl, Wh2, Wl2, h2, ats2, atd2, as2, ad2, n);
    k_agg2<<<(n + 1) / 2, 128, 0, stream>>>(h2, as2, ad2, offs, esrc, b2, out2, n, tot);

    // BN + LN
    k_bnstat<<<512, 128, 0, stream>>>(out2, bnsum, bnsq, n);
    k_final<<<(n + 3) / 4, 256, 0, stream>>>(out2, bnsum, bnsq, bng, bnb, lng, lnb,
                                             (float*)d_out, n);
}

// Round 14
// 333.176 us; speedup vs baseline: 1.0358x; 1.0358x over previous
//
#include <hip/hip_runtime.h>
#include <cstdint>
#include <cstddef>

#define HEADS   8
#define NFEAT   256
#define NOUT    128
#define NEG     0.2f
#define EPSV    1e-5f

typedef unsigned short ushort_t;
typedef __attribute__((ext_vector_type(8))) short s8v;   // 8 bf16 = 4 VGPR
typedef __attribute__((ext_vector_type(4))) float f4v;   // MFMA accum

static __device__ __forceinline__ float lrelu(float x) { return x > 0.f ? x : NEG * x; }

static __device__ __forceinline__ float bf2f(ushort_t u) {
    union { unsigned int i; float f; } v; v.i = ((unsigned int)u) << 16; return v.f;
}
static __device__ __forceinline__ ushort_t f2bf(float f) {
    union { float f; unsigned int i; } v; v.f = f;
    unsigned int x = v.i;
    return (ushort_t)((x + 0x7fff + ((x >> 16) & 1)) >> 16);   // RNE
}
static __device__ __forceinline__ float bits2f(unsigned int u) {
    union { unsigned int i; float f; } v; v.i = u; return v.f;
}
static __device__ __forceinline__ unsigned int f2bits(float f) {
    union { float f; unsigned int i; } v; v.f = f; return v.i;
}

// wave-local int64-vs-int32 detection (deterministic, identical in every wave)
static __device__ __forceinline__ int detect64(const int* __restrict__ ei, int E) {
    int lane = threadIdx.x & 63;
    long idx = 2L * ((long)lane * (E / 64)) + 1;
    int v = ei[idx];
    unsigned long long ball = __ballot(v == 0);
    return (ball == ~0ull) ? 1 : 0;
}

// ---------------------------------------------------------------------------
// fused: edge-count (CSR histogram) + W hi/lo packing (disjoint block ranges)
__global__ void k_prep(const int* __restrict__ ei, int* __restrict__ counts,
                       int E, int n, int cblocks,
                       const float* __restrict__ W1, const float* __restrict__ W2,
                       ushort_t* __restrict__ Wh1, ushort_t* __restrict__ Wl1,
                       ushort_t* __restrict__ Wh2, ushort_t* __restrict__ Wl2) {
    if (blockIdx.x < (unsigned)cblocks) {
        int is64 = detect64(ei, E);
        int i = blockIdx.x * 256 + threadIdx.x;
        if (i < E) {
            int d = ei[(size_t)(E + i) << is64];
            atomicAdd(&counts[d], 1);
        } else if (i < E + n) {
            atomicAdd(&counts[i - E], 1);
        }
    } else {
        int gid = (blockIdx.x - cblocks) * 256 + threadIdx.x;
        const float* W; ushort_t* Wh; ushort_t* Wl; int M;
        if (gid < 256 * 256) { W = W1; Wh = Wh1; Wl = Wl1; M = 256; }
        else { gid -= 256 * 256; if (gid >= 256 * 128) return; W = W2; Wh = Wh2; Wl = Wl2; M = 128; }
        int k = gid / M, nn = gid - k * M;
        int ntile = nn >> 4, j = nn & 15, kc = k >> 3, e = k & 7;
        int p = ((ntile * 32 + kc) * 16 + j) * 8 + e;     // K=256 -> K/8=32
        float v = W[(size_t)k * M + nn];
        ushort_t hi = f2bf(v);
        float r = v - bf2f(hi);
        Wh[p] = hi;
        Wl[p] = f2bf(r);
    }
}

__global__ __launch_bounds__(1024) void k_scan1(const int* __restrict__ counts,
                                                int* __restrict__ incl,
                                                int* __restrict__ bsum, int n) {
    int t = threadIdx.x, i = blockIdx.x * 1024 + t;
    int lane = t & 63, w = t >> 6;
    int v = (i < n) ? counts[i] : 0;
    int sv = v;
#pragma unroll
    for (int o = 1; o < 64; o <<= 1) { int u = __shfl_up(sv, o, 64); if (lane >= o) sv += u; }
    __shared__ int wsum[16];
    if (lane == 63) wsum[w] = sv;
    __syncthreads();
    if (w == 0) {
        int bs = (lane < 16) ? wsum[lane] : 0;
#pragma unroll
        for (int o = 1; o < 16; o <<= 1) { int u = __shfl_up(bs, o, 64); if (lane >= o) bs += u; }
        if (lane < 16) wsum[lane] = bs;
    }
    __syncthreads();
    int pre = (w > 0) ? wsum[w - 1] : 0;
    sv += pre;
    if (i < n) incl[i] = sv;
    if (t == 1023) bsum[blockIdx.x] = sv;   // raw block total
}

// scan3 with folded block-sum prefix
__global__ void k_scan3(const int* __restrict__ incl, const int* __restrict__ bsum,
                        const int* __restrict__ counts,
                        int* __restrict__ offs, int* __restrict__ cursor, int n) {
    __shared__ int pre_s;
    int chunk = blockIdx.x >> 2;            // 256-thr blocks, scan1 blocks = 1024
    if (threadIdx.x == 0) {
        int s = 0;
        for (int j = 0; j < chunk; ++j) s += bsum[j];
        pre_s = s;
    }
    __syncthreads();
    int i = blockIdx.x * 256 + threadIdx.x;
    if (i < n) {
        int v = incl[i] + pre_s;
        offs[i + 1] = v;
        cursor[i] = v - counts[i];
    }
    if (i == 0) offs[0] = 0;
}

__global__ void k_fill(const int* __restrict__ ei, int* __restrict__ cursor,
                       int* __restrict__ esrc, int E, int n) {
    int is64 = detect64(ei, E);
    int i = blockIdx.x * blockDim.x + threadIdx.x;
    if (i >= E + n) return;
    int s, d;
    if (i < E) { s = ei[(size_t)i << is64]; d = ei[(size_t)(E + i) << is64]; }
    else       { s = i - E; d = s; }
    int p = atomicAdd(&cursor[d], 1);
    esrc[p] = s;
}

// ---------------------------------------------------------------------------
// MFMA GEMM v4: bf16x3 split, fused att epilogue, single-barrier A-LDS dbuf
// + B-fragment register dbuf (next step's B issued before current MFMAs).
template <int MOUT>
__global__ __launch_bounds__(256) void k_mm(const float* __restrict__ A,
                                            const ushort_t* __restrict__ Wh,
                                            const ushort_t* __restrict__ Wl,
                                            ushort_t* __restrict__ C,
                                            const float* __restrict__ att_s,
                                            const float* __restrict__ att_d,
                                            float* __restrict__ as_o,
                                            float* __restrict__ ad_o, int n) {
    __shared__ ushort_t Ah[2][64][40];
    __shared__ ushort_t Al[2][64][40];
    const int t = threadIdx.x;
    const int lane = t & 63, w = t >> 6;     // w = column strip 0..3
    const int r0 = blockIdx.x * 64;
    const int srow = t >> 2;                 // staging row 0..63
    const int kh = (t & 3) * 8;              // staging k-offset 0/8/16/24
    const int arow = r0 + srow;
    const bool rowok = arow < n;
    const int lj = lane & 15, lk = lane >> 4;

    f4v acc[4][2];
#pragma unroll
    for (int a = 0; a < 4; ++a)
#pragma unroll
        for (int b = 0; b < 2; ++b) { f4v z = {0.f, 0.f, 0.f, 0.f}; acc[a][b] = z; }

    const float* abase = &A[(size_t)arow * 256 + kh];
    float pre[8];

#define MM_STAGE(BUF)                                                         \
    {                                                                         \
        unsigned int hw[4], lw[4];                                            \
        _Pragma("unroll")                                                     \
        for (int p = 0; p < 4; ++p) {                                         \
            unsigned int x0 = f2bits(pre[p * 2]);                             \
            unsigned int x1 = f2bits(pre[p * 2 + 1]);                         \
            unsigned int h1b = x1 & 0xffff0000u;                              \
            float lo0 = pre[p * 2] - bits2f(x0 & 0xffff0000u);                \
            float lo1 = pre[p * 2 + 1] - bits2f(h1b);                         \
            hw[p] = (x0 >> 16) | h1b;                                         \
            lw[p] = (f2bits(lo0) >> 16) | (f2bits(lo1) & 0xffff0000u);        \
        }                                                                     \
        uint4 hv = {hw[0], hw[1], hw[2], hw[3]};                              \
        uint4 lv = {lw[0], lw[1], lw[2], lw[3]};                              \
        *reinterpret_cast<uint4*>(&Ah[BUF][srow][kh]) = hv;                   \
        *reinterpret_cast<uint4*>(&Al[BUF][srow][kh]) = lv;                   \
    }

#define MM_LOADB(KB, BH, BL)                                                  \
    {                                                                         \
        const int kc0_ = (KB) >> 3;                                           \
        _Pragma("unroll")                                                     \
        for (int nf = 0; nf < 2; ++nf) {                                      \
            int ntile = (MOUT == 256 ? blockIdx.y * 8 : 0) + w * 2 + nf;      \
            size_t boff = ((size_t)(ntile * 32 + kc0_ + lk) * 16 + lj) * 8;   \
            BH[nf] = *reinterpret_cast<const s8v*>(&Wh[boff]);                \
            BL[nf] = *reinterpret_cast<const s8v*>(&Wl[boff]);                \
        }                                                                     \
    }

#define MM_STEP(KB, CUR, BH, BL, BHN, BLN)                                    \
    {                                                                         \
        if ((KB) < 224) {                                                     \
            const float* ap = abase + (KB) + 32;                              \
            _Pragma("unroll")                                                 \
            for (int q = 0; q < 2; ++q) {                                     \
                float4 v = rowok ? *reinterpret_cast<const float4*>(ap + q*4) \
                                 : float4{0.f, 0.f, 0.f, 0.f};                \
                pre[q*4+0]=v.x; pre[q*4+1]=v.y; pre[q*4+2]=v.z; pre[q*4+3]=v.w; \
            }                                                                 \
            MM_LOADB((KB) + 32, BHN, BLN);                                    \
        }                                                                     \
        s8v ah[4], al[4];                                                     \
        _Pragma("unroll")                                                     \
        for (int mf = 0; mf < 4; ++mf) {                                      \
            ah[mf] = *reinterpret_cast<const s8v*>(&Ah[CUR][mf*16+lj][lk*8]); \
            al[mf] = *reinterpret_cast<const s8v*>(&Al[CUR][mf*16+lj][lk*8]); \
        }                                                                     \
        _Pragma("unroll")                                                     \
        for (int nf = 0; nf < 2; ++nf)                                        \
            _Pragma("unroll")                                                 \
            for (int mf = 0; mf < 4; ++mf) {                                  \
                acc[mf][nf] = __builtin_amdgcn_mfma_f32_16x16x32_bf16(ah[mf], BH[nf], acc[mf][nf], 0, 0, 0); \
                acc[mf][nf] = __builtin_amdgcn_mfma_f32_16x16x32_bf16(ah[mf], BL[nf], acc[mf][nf], 0, 0, 0); \
                acc[mf][nf] = __builtin_amdgcn_mfma_f32_16x16x32_bf16(al[mf], BH[nf], acc[mf][nf], 0, 0, 0); \
            }                                                                 \
        if ((KB) < 224) MM_STAGE((CUR) ^ 1);                                  \
        __syncthreads();                                                      \
    }

    // prologue: A step-0 load + stage into buf0; B step-0 into regs
#pragma unroll
    for (int q = 0; q < 2; ++q) {
        float4 v = rowok ? *reinterpret_cast<const float4*>(abase + q * 4)
                         : float4{0.f, 0.f, 0.f, 0.f};
        pre[q * 4 + 0] = v.x; pre[q * 4 + 1] = v.y;
        pre[q * 4 + 2] = v.z; pre[q * 4 + 3] = v.w;
    }
    s8v bhA[2], blA[2], bhB[2], blB[2];
    MM_LOADB(0, bhA, blA);
    MM_STAGE(0);
    __syncthreads();

    for (int kb = 0; kb < 256; kb += 64) {
        MM_STEP(kb,      0, bhA, blA, bhB, blB);
        MM_STEP(kb + 32, 1, bhB, blB, bhA, blA);
    }

    const int colw = (MOUT == 256 ? blockIdx.y * 128 : 0) + w * 32;

    // C write (bf16)
#pragma unroll
    for (int mf = 0; mf < 4; ++mf) {
        int rr = r0 + mf * 16 + lk * 4;
#pragma unroll
        for (int nf = 0; nf < 2; ++nf) {
            int cc = colw + nf * 16 + lj;
#pragma unroll
            for (int r = 0; r < 4; ++r) {
                if (rr + r < n) C[(size_t)(rr + r) * MOUT + cc] = f2bf(acc[mf][nf][r]);
            }
        }
    }

    // fused attention-logit epilogue (reduce over this wave's 32 cols)
    float asv[2], adv[2];
#pragma unroll
    for (int nf = 0; nf < 2; ++nf) {
        asv[nf] = att_s[colw + nf * 16 + lj];
        adv[nf] = att_d[colw + nf * 16 + lj];
    }
#pragma unroll
    for (int mf = 0; mf < 4; ++mf) {
        int rr = r0 + mf * 16 + lk * 4;
#pragma unroll
        for (int r = 0; r < 4; ++r) {
            float ss = acc[mf][0][r] * asv[0] + acc[mf][1][r] * asv[1];
            float sd = acc[mf][0][r] * adv[0] + acc[mf][1][r] * adv[1];
#pragma unroll
            for (int o = 1; o < 16; o <<= 1) {
                ss += __shfl_xor(ss, o, 64); sd += __shfl_xor(sd, o, 64);
            }
            if (lj == 0 && rr + r < n) {
                if (MOUT == 256) {
                    int head = (colw >> 5);
                    as_o[(size_t)(rr + r) * 8 + head] = ss;
                    ad_o[(size_t)(rr + r) * 8 + head] = sd;
                } else {
                    atomicAdd(&as_o[rr + r], ss);
                    atomicAdd(&ad_o[rr + r], sd);
                }
            }
        }
    }
#undef MM_STEP
#undef MM_LOADB
#undef MM_STAGE
}

// ---------------------------------------------------------------------------
// layer-1 aggregation: half-wave per edge; exp once per (edge,head) in phase A.
__global__ __launch_bounds__(128) void k_agg1(const ushort_t* __restrict__ h1,
                                              const float* __restrict__ as1,
                                              const float* __restrict__ ad1,
                                              const int* __restrict__ offs,
                                              const int* __restrict__ esrc,
                                              const float* __restrict__ b1,
                                              float* __restrict__ out1, int n, int tot) {
    int wid = (blockIdx.x * 128 + threadIdx.x) >> 6;
    int lane = threadIdx.x & 63;
    if (wid >= n) return;
    int e0 = offs[wid], e1 = offs[wid + 1];
    int deg = e1 - e0;

    if (deg <= 64) {
        const int l = lane & 31;          // channel-group lane
        const int h = lane >> 5;          // half: edge parity
        const int hd = l >> 2;            // head owning channels l*8..l*8+7
        const int cb = l * 8;

        int ei_idx = e0 + lane;
        int es = esrc[ei_idx < tot ? ei_idx : (tot - 1)];

        const int headA = lane >> 3, g = lane & 7;
        float adnA = ad1[(size_t)wid * 8 + headA];
        float a[8];
#pragma unroll
        for (int k = 0; k < 8; ++k) {
            int i = g + 8 * k;
            int s = __shfl(es, i, 64);
            a[k] = (i < deg) ? as1[(size_t)s * 8 + headA] : -1e30f;
        }
        float mx = a[0];
#pragma unroll
        for (int k = 1; k < 8; ++k) mx = fmaxf(mx, a[k]);
#pragma unroll
        for (int o = 1; o < 8; o <<= 1) mx = fmaxf(mx, __shfl_xor(mx, o, 64));
        float mA = lrelu(mx + adnA);
#pragma unroll
        for (int k = 0; k < 8; ++k)
            a[k] = __expf(lrelu(a[k] + adnA) - mA);   // p, 0 for padding

        float d = 0.f;
        float ac0 = 0.f, ac1 = 0.f, ac2 = 0.f, ac3 = 0.f;
        float ac4 = 0.f, ac5 = 0.f, ac6 = 0.f, ac7 = 0.f;
#pragma unroll
        for (int u = 0; u < 8; ++u) {
            if (8 * u < deg) {
#pragma unroll
                for (int v = 0; v < 4; ++v) {
                    int i = 8 * u + 2 * v + h;
                    int s = __shfl(es, i, 64);
                    float p = __shfl(a[u], hd * 8 + 2 * v + h, 64);
                    if (i < deg) {
                        uint4 hv = *reinterpret_cast<const uint4*>(&h1[(size_t)s * 256 + cb]);
                        d += p;
                        ac0 += p * bits2f(hv.x << 16);
                        ac1 += p * bits2f(hv.x & 0xffff0000u);
                        ac2 += p * bits2f(hv.y << 16);
                        ac3 += p * bits2f(hv.y & 0xffff0000u);
                        ac4 += p * bits2f(hv.z << 16);
                        ac5 += p * bits2f(hv.z & 0xffff0000u);
                        ac6 += p * bits2f(hv.w << 16);
                        ac7 += p * bits2f(hv.w & 0xffff0000u);
                    }
                }
            }
        }
        d   += __shfl_xor(d, 32, 64);
        ac0 += __shfl_xor(ac0, 32, 64); ac1 += __shfl_xor(ac1, 32, 64);
        ac2 += __shfl_xor(ac2, 32, 64); ac3 += __shfl_xor(ac3, 32, 64);
        ac4 += __shfl_xor(ac4, 32, 64); ac5 += __shfl_xor(ac5, 32, 64);
        ac6 += __shfl_xor(ac6, 32, 64); ac7 += __shfl_xor(ac7, 32, 64);
        if (lane < 32) {
            float inv = 1.f / (d + 1e-16f);
            float4 b0 = *reinterpret_cast<const float4*>(&b1[cb]);
            float4 b4 = *reinterpret_cast<const float4*>(&b1[cb + 4]);
            float4 o0, o1;
            o0.x = fmaxf(ac0 * inv + b0.x, 0.f);
            o0.y = fmaxf(ac1 * inv + b0.y, 0.f);
            o0.z = fmaxf(ac2 * inv + b0.z, 0.f);
            o0.w = fmaxf(ac3 * inv + b0.w, 0.f);
            o1.x = fmaxf(ac4 * inv + b4.x, 0.f);
            o1.y = fmaxf(ac5 * inv + b4.y, 0.f);
            o1.z = fmaxf(ac6 * inv + b4.z, 0.f);
            o1.w = fmaxf(ac7 * inv + b4.w, 0.f);
            *reinterpret_cast<float4*>(&out1[(size_t)wid * 256 + cb]) = o0;
            *reinterpret_cast<float4*>(&out1[(size_t)wid * 256 + cb + 4]) = o1;
        }
    } else {
        int head = lane >> 3;
        int g = lane & 7;
        int cb = lane * 4;
        float adn = ad1[(size_t)wid * 8 + head];
        float mx = -1e30f;
        for (int e = e0 + g; e < e1; e += 8)
            mx = fmaxf(mx, as1[(size_t)esrc[e] * 8 + head]);
#pragma unroll
        for (int o = 1; o < 8; o <<= 1) mx = fmaxf(mx, __shfl_xor(mx, o, 64));
        float m = lrelu(mx + adn);
        float d = 0.f, ax = 0.f, ay = 0.f, az = 0.f, aw = 0.f;
        for (int e = e0; e < e1; ++e) {
            int s = esrc[e];
            float p = __expf(lrelu(as1[(size_t)s * 8 + head] + adn) - m);
            ushort4 hv = *reinterpret_cast<const ushort4*>(&h1[(size_t)s * 256 + cb]);
            d += p;
            ax += p * bf2f(hv.x);
            ay += p * bf2f(hv.y);
            az += p * bf2f(hv.z);
            aw += p * bf2f(hv.w);
        }
        float inv = 1.f / (d + 1e-16f);
        float4 bb = *reinterpret_cast<const float4*>(&b1[cb]);
        float4 o;
        o.x = fmaxf(ax * inv + bb.x, 0.f);
        o.y = fmaxf(ay * inv + bb.y, 0.f);
        o.z = fmaxf(az * inv + bb.z, 0.f);
        o.w = fmaxf(aw * inv + bb.w, 0.f);
        *reinterpret_cast<float4*>(&out1[(size_t)wid * 256 + cb]) = o;
    }
}

// layer-2 aggregation: quarter-wave per edge; exp once per edge.
__global__ __launch_bounds__(128) void k_agg2(const ushort_t* __restrict__ h2,
                                              const float* __restrict__ as2,
                                              const float* __restrict__ ad2,
                                              const int* __restrict__ offs,
                                              const int* __restrict__ esrc,
                                              const float* __restrict__ b2,
                                              float* __restrict__ out2, int n, int tot) {
    int wid = (blockIdx.x * 128 + threadIdx.x) >> 6;
    int lane = threadIdx.x & 63;
    if (wid >= n) return;
    float adn = ad2[wid];
    int e0 = offs[wid], e1 = offs[wid + 1];
    int deg = e1 - e0;

    if (deg <= 64) {
        const int l = lane & 15;
        const int q = lane >> 4;
        const int cb = l * 8;

        int ei_idx = e0 + lane;
        int es = esrc[ei_idx < tot ? ei_idx : (tot - 1)];
        float av0 = (lane < deg) ? as2[es] : -1e30f;
        float mx = av0;
#pragma unroll
        for (int o = 1; o < 64; o <<= 1) mx = fmaxf(mx, __shfl_xor(mx, o, 64));
        float m = lrelu(mx + adn);
        float p0 = __expf(lrelu(av0 + adn) - m);   // one exp per edge

        float d = 0.f;
        float ac0 = 0.f, ac1 = 0.f, ac2 = 0.f, ac3 = 0.f;
        float ac4 = 0.f, ac5 = 0.f, ac6 = 0.f, ac7 = 0.f;
#pragma unroll
        for (int u = 0; u < 4; ++u) {
            if (16 * u < deg) {
#pragma unroll
                for (int v = 0; v < 4; ++v) {
                    int i = 16 * u + 4 * v + q;
                    int s = __shfl(es, i, 64);
                    float p = __shfl(p0, i, 64);
                    if (i < deg) {
                        uint4 hv = *reinterpret_cast<const uint4*>(&h2[(size_t)s * 128 + cb]);
                        d += p;
                        ac0 += p * bits2f(hv.x << 16);
                        ac1 += p * bits2f(hv.x & 0xffff0000u);
                        ac2 += p * bits2f(hv.y << 16);
                        ac3 += p * bits2f(hv.y & 0xffff0000u);
                        ac4 += p * bits2f(hv.z << 16);
                        ac5 += p * bits2f(hv.z & 0xffff0000u);
                        ac6 += p * bits2f(hv.w << 16);
                        ac7 += p * bits2f(hv.w & 0xffff0000u);
                    }
                }
            }
        }
#pragma unroll
        for (int o = 16; o <= 32; o <<= 1) {
            d   += __shfl_xor(d, o, 64);
            ac0 += __shfl_xor(ac0, o, 64); ac1 += __shfl_xor(ac1, o, 64);
            ac2 += __shfl_xor(ac2, o, 64); ac3 += __shfl_xor(ac3, o, 64);
            ac4 += __shfl_xor(ac4, o, 64); ac5 += __shfl_xor(ac5, o, 64);
            ac6 += __shfl_xor(ac6, o, 64); ac7 += __shfl_xor(ac7, o, 64);
        }
        if (lane < 16) {
            float inv = 1.f / (d + 1e-16f);
            float4 b0 = *reinterpret_cast<const float4*>(&b2[cb]);
            float4 b4 = *reinterpret_cast<const float4*>(&b2[cb + 4]);
            float4 o0, o1;
            o0.x = fmaxf(ac0 * inv + b0.x, 0.f);
            o0.y = fmaxf(ac1 * inv + b0.y, 0.f);
            o0.z = fmaxf(ac2 * inv + b0.z, 0.f);
            o0.w = fmaxf(ac3 * inv + b0.w, 0.f);
            o1.x = fmaxf(ac4 * inv + b4.x, 0.f);
            o1.y = fmaxf(ac5 * inv + b4.y, 0.f);
            o1.z = fmaxf(ac6 * inv + b4.z, 0.f);
            o1.w = fmaxf(ac7 * inv + b4.w, 0.f);
            *reinterpret_cast<float4*>(&out2[(size_t)wid * 128 + cb]) = o0;
            *reinterpret_cast<float4*>(&out2[(size_t)wid * 128 + cb + 4]) = o1;
        }
    } else {
        int cb = lane * 2;
        float mx = -1e30f;
        for (int e = e0 + lane; e < e1; e += 64)
            mx = fmaxf(mx, as2[esrc[e]]);
#pragma unroll
        for (int o = 1; o < 64; o <<= 1) mx = fmaxf(mx, __shfl_xor(mx, o, 64));
        float m = lrelu(mx + adn);
        float d = 0.f, ax = 0.f, ay = 0.f;
        for (int e = e0; e < e1; ++e) {
            int s = esrc[e];
            float p = __expf(lrelu(as2[s] + adn) - m);
            ushort2 hv = *reinterpret_cast<const ushort2*>(&h2[(size_t)s * 128 + cb]);
            d += p;
            ax += p * bf2f(hv.x);
            ay += p * bf2f(hv.y);
        }
        float inv = 1.f / (d + 1e-16f);
        float o0 = fmaxf(ax * inv + b2[cb], 0.f);
        float o1 = fmaxf(ay * inv + b2[cb + 1], 0.f);
        float2 o = {o0, o1};
        *reinterpret_cast<float2*>(&out2[(size_t)wid * 128 + cb]) = o;
    }
}

// ---------------------------------------------------------------------------
__global__ __launch_bounds__(128) void k_bnstat(const float* __restrict__ out2,
                                                float* __restrict__ bnsum,
                                                float* __restrict__ bnsq, int n) {
    int c = threadIdx.x;
    float s = 0.f, q = 0.f;
    for (int r = blockIdx.x; r < n; r += gridDim.x) {
        float v = out2[(size_t)r * 128 + c];
        s += v;
        q += v * v;
    }
    atomicAdd(&bnsum[c], s);
    atomicAdd(&bnsq[c], q);
}

__global__ __launch_bounds__(256) void k_final(const float* __restrict__ out2,
                                               const float* __restrict__ bnsum,
                                               const float* __restrict__ bnsq,
                                               const float* __restrict__ bng,
                                               const float* __restrict__ bnb,
                                               const float* __restrict__ lng,
                                               const float* __restrict__ lnb,
                                               float* __restrict__ out, int n) {
    int wid = (blockIdx.x * blockDim.x + threadIdx.x) >> 6;
    int lane = threadIdx.x & 63;
    if (wid >= n) return;
    int c0 = lane, c1 = lane + 64;
    float invn = 1.f / (float)n;
    float mu0 = bnsum[c0] * invn, mu1 = bnsum[c1] * invn;
    float v0 = bnsq[c0] * invn - mu0 * mu0;
    float v1 = bnsq[c1] * invn - mu1 * mu1;
    float r0 = rsqrtf(v0 + EPSV), r1 = rsqrtf(v1 + EPSV);
    float x0 = out2[(size_t)wid * 128 + c0];
    float x1 = out2[(size_t)wid * 128 + c1];
    float y0 = (x0 - mu0) * r0 * bng[c0] + bnb[c0];
    float y1 = (x1 - mu1) * r1 * bng[c1] + bnb[c1];
    float s = y0 + y1, q = y0 * y0 + y1 * y1;
#pragma unroll
    for (int o = 1; o < 64; o <<= 1) { s += __shfl_xor(s, o, 64); q += __shfl_xor(q, o, 64); }
    float mu = s * (1.f / 128.f);
    float var = q * (1.f / 128.f) - mu * mu;
    float rr = rsqrtf(var + EPSV);
    out[(size_t)wid * 128 + c0] = (y0 - mu) * rr * lng[c0] + lnb[c0];
    out[(size_t)wid * 128 + c1] = (y1 - mu) * rr * lng[c1] + lnb[c1];
}

// ---------------------------------------------------------------------------
extern "C" void kernel_launch(void* const* d_in, const int* in_sizes, int n_in,
                              void* d_out, int out_size, void* d_ws, size_t ws_size,
                              hipStream_t stream) {
    const float* x    = (const float*)d_in[0];
    const int*   ei   = (const int*)d_in[1];
    const float* W1   = (const float*)d_in[2];
    const float* ats1 = (const float*)d_in[3];
    const float* atd1 = (const float*)d_in[4];
    const float* b1   = (const float*)d_in[5];
    const float* W2   = (const float*)d_in[6];
    const float* ats2 = (const float*)d_in[7];
    const float* atd2 = (const float*)d_in[8];
    const float* b2   = (const float*)d_in[9];
    const float* bng  = (const float*)d_in[10];
    const float* bnb  = (const float*)d_in[11];
    const float* lng  = (const float*)d_in[12];
    const float* lnb  = (const float*)d_in[13];

    const int n = in_sizes[0] / NFEAT;   // 50000
    const int E = in_sizes[1] / 2;       // 800000
    const int tot = E + n;

    auto align = [](size_t v) { return (v + 255) & ~(size_t)255; };
    char* ws = (char*)d_ws;
    size_t off = 0;
    ushort_t* h1 = (ushort_t*)(ws + off); off += align((size_t)n * 256 * 2);
    float* out1 = (float*)(ws + off); off += align((size_t)n * 256 * 4);
    ushort_t* h2 = h1;
    float* out2 = out1;
    float* as1 = (float*)(ws + off); off += align((size_t)n * 8 * 4);
    float* ad1 = (float*)(ws + off); off += align((size_t)n * 8 * 4);
    // zero-region: counts[n] | bnsum[128] | bnsq[128] | as2[n] | ad2[n]
    int* counts = (int*)(ws + off); off += align((size_t)n * 12 + 1024);
    float* bnsum = (float*)(counts + n);
    float* bnsq  = bnsum + 128;
    float* as2   = bnsq + 128;
    float* ad2   = as2 + n;
    int* offs   = (int*)(ws + off); off += align((size_t)(n + 1) * 4);
    int* cursor = (int*)(ws + off); off += align((size_t)n * 4);
    int* esrc   = (int*)(ws + off); off += align((size_t)tot * 4);
    int* incl   = (int*)(ws + off); off += align((size_t)n * 4);
    int* bsum   = (int*)(ws + off); off += align(64 * 4);
    ushort_t* Wh1 = (ushort_t*)(ws + off); off += align((size_t)256 * 256 * 2);
    ushort_t* Wl1 = (ushort_t*)(ws + off); off += align((size_t)256 * 256 * 2);
    ushort_t* Wh2 = (ushort_t*)(ws + off); off += align((size_t)256 * 128 * 2);
    ushort_t* Wl2 = (ushort_t*)(ws + off); off += align((size_t)256 * 128 * 2);

    hipMemsetAsync(counts, 0, (size_t)n * 12 + 1024, stream);

    // fused count + W-pack
    const int cblocks = (tot + 255) / 256;
    const int pblocks = (256 * 256 + 256 * 128 + 255) / 256;
    k_prep<<<cblocks + pblocks, 256, 0, stream>>>(ei, counts, E, n, cblocks,
                                                  W1, W2, Wh1, Wl1, Wh2, Wl2);
    int nsb = (n + 1023) / 1024;
    k_scan1<<<nsb, 1024, 0, stream>>>(counts, incl, bsum, n);
    k_scan3<<<(n + 255) / 256, 256, 0, stream>>>(incl, bsum, counts, offs, cursor, n);
    k_fill<<<(tot + 255) / 256, 256, 0, stream>>>(ei, cursor, esrc, E, n);

    const int gx = (n + 63) / 64;
    // layer 1 (att logits fused into GEMM epilogue)
    k_mm<256><<<dim3(gx, 2), 256, 0, stream>>>(x, Wh1, Wl1, h1, ats1, atd1, as1, ad1, n);
    k_agg1<<<(n + 1) / 2, 128, 0, stream>>>(h1, as1, ad1, offs, esrc, b1, out1, n, tot);

    // layer 2 (att logits fused, atomic partials into zeroed as2/ad2)
    k_mm<128><<<dim3(gx, 1), 256, 0, stream>>>(out1, Wh2, Wl2, h2, ats2, atd2, as2, ad2, n);
    k_agg2<<<(n + 1) / 2, 128, 0, stream>>>(h2, as2, ad2, offs, esrc, b2, out2, n, tot);

    // BN + LN
    k_bnstat<<<512, 128, 0, stream>>>(out2, bnsum, bnsq, n);
    k_final<<<(n + 3) / 4, 256, 0, stream>>>(out2, bnsum, bnsq, bng, bnb, lng, lnb,
                                             (float*)d_out, n);
}